// Round 4
// baseline (277.794 us; speedup 1.0000x reference)
//
#include <hip/hip_runtime.h>
#include <hip/hip_bf16.h>

// B=4, L=4096, D=1024; M = B*L = 16384. ALL I/O IS FP32 (per reference).
// Live path: h = (x@Wp[:,0:D]) * sigmoid(x@Wp[:,2D:3D]); out = h@W_out + b_out
// Internals: bf16 MFMA with fp32 accumulation (error ~0.02 < 0.058 threshold).
//
// Memory plan (d_out = 64 MB fp32; ws usage = 22 MB):
//   d_out bytes [0,32M)  : Xbf16 (phases 1-3), then out rows 0..8191 fp32 (gemm2a)
//   d_out bytes [32,64M) : H bf16 (gemm1), then out rows 8192..16383 fp32 (gemm2b)
//   ws shorts [0,3M)     : WgT | WoT | WoutT bf16 panels (6 MB)
//   ws shorts [3M,11M)   : copy of H rows 8192..16383 (16 MB), read by gemm2b

#define MTOT 16384
#define DM   1024
#define MEG  (1024 * 1024)

typedef __bf16 bf16x8 __attribute__((ext_vector_type(8)));
typedef float  f32x4  __attribute__((ext_vector_type(4)));

#define AS1 __attribute__((address_space(1)))
#define AS3 __attribute__((address_space(3)))

static __device__ __forceinline__ void async_load16(const void* g, void* l) {
    __builtin_amdgcn_global_load_lds((const AS1 void*)g, (AS3 void*)l, 16, 0, 0);
}

static __device__ __forceinline__ unsigned short f2bf(float f) {
    __hip_bfloat16 h = __float2bfloat16(f);
    return *(unsigned short*)&h;
}

// ---------------- x (fp32) -> Xbf16 ------------------------------------------
__global__ __launch_bounds__(256)
void conv_x(const float* __restrict__ x, unsigned short* __restrict__ dst) {
    const size_t i = ((size_t)blockIdx.x * 256 + threadIdx.x) * 8;
    const f32x4 a = *(const f32x4*)(x + i);
    const f32x4 b = *(const f32x4*)(x + i + 4);
    __align__(16) unsigned short o[8];
    o[0] = f2bf(a[0]); o[1] = f2bf(a[1]); o[2] = f2bf(a[2]); o[3] = f2bf(a[3]);
    o[4] = f2bf(b[0]); o[5] = f2bf(b[1]); o[6] = f2bf(b[2]); o[7] = f2bf(b[3]);
    *(uint4*)(dst + i) = *(const uint4*)o;
}

// -------- weight transpose+convert: dst[n][k] = bf16(src[k][coff+n]) ---------
__global__ void transpose_w(const float* __restrict__ Wproj, const float* __restrict__ Wout,
                            unsigned short* __restrict__ dst0) {
    __shared__ unsigned short t[32][33];
    const int z = blockIdx.z;
    const float* src;
    unsigned short* dst;
    int ld, coff;
    if (z == 0)      { src = Wproj; ld = 3072; coff = 0;    dst = dst0; }
    else if (z == 1) { src = Wproj; ld = 3072; coff = 2048; dst = dst0 + MEG; }
    else             { src = Wout;  ld = 1024; coff = 0;    dst = dst0 + 2 * MEG; }
    const int k0 = blockIdx.x * 32;
    const int n0 = blockIdx.y * 32;
    const int tx = threadIdx.x, ty = threadIdx.y;
    for (int i = ty; i < 32; i += 8)
        t[i][tx] = f2bf(src[(size_t)(k0 + i) * ld + coff + n0 + tx]);
    __syncthreads();
    for (int i = ty; i < 32; i += 8)
        dst[(size_t)(n0 + i) * DM + k0 + tx] = t[tx][i];
}

// ---------- GEMM1 fused: H = (X@Wg + bg) * sigmoid(X@Wo + bo) ---------------
// 256 thr / 4 waves; BM=128, BN=64 per matrix (x2 matrices), BK=32;
// 16 MFMA(16x16x32)/wave/K-step — verified m97 mix.
__global__ __launch_bounds__(256, 2)
void gemm1_fused(const unsigned short* __restrict__ X,
                 const unsigned short* __restrict__ WgT,
                 const unsigned short* __restrict__ WoT,
                 const float* __restrict__ bproj,
                 unsigned short* __restrict__ H) {
    __shared__ __align__(16) unsigned short sA[128 * 32];
    __shared__ __align__(16) unsigned short sBg[64 * 32];
    __shared__ __align__(16) unsigned short sBo[64 * 32];

    const int tid  = threadIdx.x;
    const int wave = tid >> 6;
    const int lane = tid & 63;
    const int m0 = blockIdx.y * 128;
    const int n0 = blockIdx.x * 64;
    const int wm = (wave & 1) * 64;
    const int wn = (wave >> 1) * 32;

    f32x4 accG[4][2], accO[4][2];
#pragma unroll
    for (int i = 0; i < 4; ++i)
#pragma unroll
        for (int j = 0; j < 2; ++j) {
            accG[i][j] = (f32x4){0.f, 0.f, 0.f, 0.f};
            accO[i][j] = (f32x4){0.f, 0.f, 0.f, 0.f};
        }

    const int arow = tid >> 2;        // 0..63
    const int acol = (tid & 3) * 8;   // 0,8,16,24
    const int kq = (lane >> 4) * 8;
    const int rA = lane & 15;

    for (int k0 = 0; k0 < DM; k0 += 32) {
        async_load16(X + (size_t)(m0 + arow) * DM + k0 + acol,       (char*)sA + tid * 16);
        async_load16(X + (size_t)(m0 + 64 + arow) * DM + k0 + acol,  (char*)sA + 4096 + tid * 16);
        async_load16(WgT + (size_t)(n0 + arow) * DM + k0 + acol,     (char*)sBg + tid * 16);
        async_load16(WoT + (size_t)(n0 + arow) * DM + k0 + acol,     (char*)sBo + tid * 16);
        __syncthreads();

        bf16x8 af[4], bg[2], bo[2];
#pragma unroll
        for (int i = 0; i < 4; ++i)
            af[i] = *(const bf16x8*)&sA[(wm + i * 16 + rA) * 32 + kq];
#pragma unroll
        for (int j = 0; j < 2; ++j) {
            bg[j] = *(const bf16x8*)&sBg[(wn + j * 16 + rA) * 32 + kq];
            bo[j] = *(const bf16x8*)&sBo[(wn + j * 16 + rA) * 32 + kq];
        }
#pragma unroll
        for (int i = 0; i < 4; ++i)
#pragma unroll
            for (int j = 0; j < 2; ++j) {
                accG[i][j] = __builtin_amdgcn_mfma_f32_16x16x32_bf16(af[i], bg[j], accG[i][j], 0, 0, 0);
                accO[i][j] = __builtin_amdgcn_mfma_f32_16x16x32_bf16(af[i], bo[j], accO[i][j], 0, 0, 0);
            }
        __syncthreads();
    }

    const int colL = lane & 15;
    const int rowQ = (lane >> 4) * 4;
#pragma unroll
    for (int j = 0; j < 2; ++j) {
        const int n = n0 + wn + j * 16 + colL;
        const float bgv = bproj[n];
        const float bov = bproj[2048 + n];
#pragma unroll
        for (int i = 0; i < 4; ++i) {
            const int mbase = m0 + wm + i * 16 + rowQ;
#pragma unroll
            for (int r = 0; r < 4; ++r) {
                const float g = accG[i][j][r] + bgv;
                const float o = accO[i][j][r] + bov;
                const float h = g * (1.0f / (1.0f + __expf(-o)));
                H[(size_t)(mbase + r) * DM + n] = f2bf(h);
            }
        }
    }
}

// -------- GEMM2 half: Out[row_base + m][:] = A_half[m][:] @ WoutT^T + b ------
// A_half is an 8192-row bf16 [m][k] panel; Out is the full fp32 output.
__global__ __launch_bounds__(256, 2)
void gemm2(const unsigned short* __restrict__ A,
           const unsigned short* __restrict__ Bt,
           const float* __restrict__ bout,
           float* __restrict__ Out,
           int out_row_base) {
    __shared__ __align__(16) unsigned short sA[128 * 32];
    __shared__ __align__(16) unsigned short sB[128 * 32];

    const int tid  = threadIdx.x;
    const int wave = tid >> 6;
    const int lane = tid & 63;
    const int m0 = blockIdx.y * 128;   // local row in the half
    const int n0 = blockIdx.x * 128;
    const int wm = (wave & 1) * 64;
    const int wn = (wave >> 1) * 64;

    f32x4 acc[4][4];
#pragma unroll
    for (int i = 0; i < 4; ++i)
#pragma unroll
        for (int j = 0; j < 4; ++j) acc[i][j] = (f32x4){0.f, 0.f, 0.f, 0.f};

    const int arow = tid >> 2;
    const int acol = (tid & 3) * 8;
    const int kq = (lane >> 4) * 8;
    const int rA = lane & 15;

    for (int k0 = 0; k0 < DM; k0 += 32) {
        async_load16(A + (size_t)(m0 + arow) * DM + k0 + acol,      (char*)sA + tid * 16);
        async_load16(A + (size_t)(m0 + 64 + arow) * DM + k0 + acol, (char*)sA + 4096 + tid * 16);
        async_load16(Bt + (size_t)(n0 + arow) * DM + k0 + acol,      (char*)sB + tid * 16);
        async_load16(Bt + (size_t)(n0 + 64 + arow) * DM + k0 + acol, (char*)sB + 4096 + tid * 16);
        __syncthreads();

        bf16x8 af[4], bfr[4];
#pragma unroll
        for (int i = 0; i < 4; ++i)
            af[i] = *(const bf16x8*)&sA[(wm + i * 16 + rA) * 32 + kq];
#pragma unroll
        for (int j = 0; j < 4; ++j)
            bfr[j] = *(const bf16x8*)&sB[(wn + j * 16 + rA) * 32 + kq];
#pragma unroll
        for (int i = 0; i < 4; ++i)
#pragma unroll
            for (int j = 0; j < 4; ++j)
                acc[i][j] = __builtin_amdgcn_mfma_f32_16x16x32_bf16(af[i], bfr[j], acc[i][j], 0, 0, 0);
        __syncthreads();
    }

    const int colL = lane & 15;
    const int rowQ = (lane >> 4) * 4;
#pragma unroll
    for (int j = 0; j < 4; ++j) {
        const int n = n0 + wn + j * 16 + colL;
        const float bv = bout[n];
#pragma unroll
        for (int i = 0; i < 4; ++i) {
            const int mbase = out_row_base + m0 + wm + i * 16 + rowQ;
#pragma unroll
            for (int r = 0; r < 4; ++r)
                Out[(size_t)(mbase + r) * DM + n] = acc[i][j][r] + bv;
        }
    }
}

extern "C" void kernel_launch(void* const* d_in, const int* in_sizes, int n_in,
                              void* d_out, int out_size, void* d_ws, size_t ws_size,
                              hipStream_t stream) {
    const float* x     = (const float*)d_in[0];   // [4,4096,1024] fp32
    const float* Wproj = (const float*)d_in[1];   // [1024,3072]   fp32
    const float* bproj = (const float*)d_in[2];   // [3072]        fp32 (zeros)
    const float* Wout  = (const float*)d_in[3];   // [1024,1024]   fp32
    const float* bout  = (const float*)d_in[4];   // [1024]        fp32 (zeros)
    float* out = (float*)d_out;                   // [4,4096,1024] fp32 (64 MB)

    unsigned short* Xb    = (unsigned short*)d_out;            // shorts [0,16M)
    unsigned short* Hfull = (unsigned short*)d_out + 16 * MEG; // shorts [16M,32M) = bytes [32,64M)
    unsigned short* WgT   = (unsigned short*)d_ws;             // ws shorts [0,1M)
    unsigned short* WoT   = WgT + MEG;                         // ws shorts [1M,2M)
    unsigned short* WoutT = WgT + 2 * MEG;                     // ws shorts [2M,3M)
    unsigned short* Hhi   = WgT + 3 * MEG;                     // ws shorts [3M,11M) = 16 MB

    // 1) Xbf16 (d_out lo) <- fp32 x
    conv_x<<<(MTOT * DM) / (256 * 8), 256, 0, stream>>>(x, Xb);

    // 2) transposed bf16 weight panels -> ws
    transpose_w<<<dim3(32, 32, 3), dim3(32, 8, 1), 0, stream>>>(Wproj, Wout, WgT);

    // 3) H (d_out hi) = (X@Wg + bg) * sigmoid(X@Wo + bo)
    gemm1_fused<<<dim3(DM / 64, MTOT / 128), 256, 0, stream>>>(Xb, WgT, WoT, bproj, Hfull);

    // 4) stash H rows 8192..16383 into ws (gemm2b will overwrite that d_out region)
    hipMemcpyAsync(Hhi, Hfull + (size_t)8192 * DM, (size_t)8192 * DM * 2,
                   hipMemcpyDeviceToDevice, stream);

    // 5) out rows [0,8192): reads H-lo (d_out hi, disjoint from writes) + ws
    gemm2<<<dim3(DM / 128, 64), 256, 0, stream>>>(Hfull, WoutT, bout, out, 0);

    // 6) out rows [8192,16384): reads only ws, overwrites the H region
    gemm2<<<dim3(DM / 128, 64), 256, 0, stream>>>(Hhi, WoutT, bout, out, 8192);
}

// Round 5
// 266.085 us; speedup vs baseline: 1.0440x; 1.0440x over previous
//
#include <hip/hip_runtime.h>
#include <hip/hip_bf16.h>

// B=4, L=4096, D=1024; M = B*L = 16384. ALL I/O IS FP32.
// Live path: h = (x@Wp[:,0:D]) * sigmoid(x@Wp[:,2D:3D]); out = h@W_out + b_out
// Internals: bf16 MFMA, fp32 accumulation (absmax 0.0156 < 0.058 threshold, R4).
//
// Memory plan (ws_size-adaptive, branch is constant across calls => graph-safe):
//   ws shorts [0,3M)   : WgT | WoT | WoutT bf16 panels (6 MB)
//   BIG ws (>=38 MB)   : H (16M shorts) entirely at ws+3M; single gemm2 launch.
//   SMALL ws           : H rows 0..8191 -> d_out shorts [16M,24M);
//                        H rows 8192..  -> ws+3M (8M shorts);
//                        two sequential gemm2 halves (lo first: reads d_out-hi,
//                        writes d_out-lo; hi second: reads ws, overwrites dead H-lo).
//   d_out shorts [0,16M): Xbf16 during phases 1-3, then fp32 out rows 0..8191.

#define MTOT 16384
#define DM   1024
#define MEG  (1024 * 1024)

typedef __bf16 bf16x8 __attribute__((ext_vector_type(8)));
typedef float  f32x4  __attribute__((ext_vector_type(4)));

#define AS1 __attribute__((address_space(1)))
#define AS3 __attribute__((address_space(3)))

static __device__ __forceinline__ void async_load16(const void* g, void* l) {
    __builtin_amdgcn_global_load_lds((const AS1 void*)g, (AS3 void*)l, 16, 0, 0);
}

static __device__ __forceinline__ unsigned short f2bf(float f) {
    __hip_bfloat16 h = __float2bfloat16(f);
    return *(unsigned short*)&h;
}

// ---------------- x (fp32) -> Xbf16 ------------------------------------------
__global__ __launch_bounds__(256)
void conv_x(const float* __restrict__ x, unsigned short* __restrict__ dst) {
    const size_t i = ((size_t)blockIdx.x * 256 + threadIdx.x) * 8;
    const f32x4 a = *(const f32x4*)(x + i);
    const f32x4 b = *(const f32x4*)(x + i + 4);
    __align__(16) unsigned short o[8];
    o[0] = f2bf(a[0]); o[1] = f2bf(a[1]); o[2] = f2bf(a[2]); o[3] = f2bf(a[3]);
    o[4] = f2bf(b[0]); o[5] = f2bf(b[1]); o[6] = f2bf(b[2]); o[7] = f2bf(b[3]);
    *(uint4*)(dst + i) = *(const uint4*)o;
}

// -------- weight transpose+convert: dst[n][k] = bf16(src[k][coff+n]) ---------
__global__ void transpose_w(const float* __restrict__ Wproj, const float* __restrict__ Wout,
                            unsigned short* __restrict__ dst0) {
    __shared__ unsigned short t[32][33];
    const int z = blockIdx.z;
    const float* src;
    unsigned short* dst;
    int ld, coff;
    if (z == 0)      { src = Wproj; ld = 3072; coff = 0;    dst = dst0; }
    else if (z == 1) { src = Wproj; ld = 3072; coff = 2048; dst = dst0 + MEG; }
    else             { src = Wout;  ld = 1024; coff = 0;    dst = dst0 + 2 * MEG; }
    const int k0 = blockIdx.x * 32;
    const int n0 = blockIdx.y * 32;
    const int tx = threadIdx.x, ty = threadIdx.y;
    for (int i = ty; i < 32; i += 8)
        t[i][tx] = f2bf(src[(size_t)(k0 + i) * ld + coff + n0 + tx]);
    __syncthreads();
    for (int i = ty; i < 32; i += 8)
        dst[(size_t)(n0 + i) * DM + k0 + tx] = t[tx][i];
}

// ---------- GEMM1 fused: H = (X@Wg + bg) * sigmoid(X@Wo + bo) ---------------
// 256 thr / 4 waves; BM=128, BN=64 per matrix (x2 matrices), BK=32;
// 16 MFMA(16x16x32)/wave/K-step (verified m97 mix). H store is split:
// rows < 8192 -> Hlo base, rows >= 8192 -> Hhi base (block-uniform select).
__global__ __launch_bounds__(256, 2)
void gemm1_fused(const unsigned short* __restrict__ X,
                 const unsigned short* __restrict__ WgT,
                 const unsigned short* __restrict__ WoT,
                 const float* __restrict__ bproj,
                 unsigned short* __restrict__ Hlo,
                 unsigned short* __restrict__ Hhi) {
    __shared__ __align__(16) unsigned short sA[128 * 32];
    __shared__ __align__(16) unsigned short sBg[64 * 32];
    __shared__ __align__(16) unsigned short sBo[64 * 32];

    const int tid  = threadIdx.x;
    const int wave = tid >> 6;
    const int lane = tid & 63;
    const int m0 = blockIdx.y * 128;
    const int n0 = blockIdx.x * 64;
    const int wm = (wave & 1) * 64;
    const int wn = (wave >> 1) * 32;

    unsigned short* __restrict__ H =
        (m0 < 8192) ? Hlo : (Hhi - (size_t)8192 * DM);

    f32x4 accG[4][2], accO[4][2];
#pragma unroll
    for (int i = 0; i < 4; ++i)
#pragma unroll
        for (int j = 0; j < 2; ++j) {
            accG[i][j] = (f32x4){0.f, 0.f, 0.f, 0.f};
            accO[i][j] = (f32x4){0.f, 0.f, 0.f, 0.f};
        }

    const int arow = tid >> 2;        // 0..63
    const int acol = (tid & 3) * 8;   // 0,8,16,24
    const int kq = (lane >> 4) * 8;
    const int rA = lane & 15;

    for (int k0 = 0; k0 < DM; k0 += 32) {
        async_load16(X + (size_t)(m0 + arow) * DM + k0 + acol,       (char*)sA + tid * 16);
        async_load16(X + (size_t)(m0 + 64 + arow) * DM + k0 + acol,  (char*)sA + 4096 + tid * 16);
        async_load16(WgT + (size_t)(n0 + arow) * DM + k0 + acol,     (char*)sBg + tid * 16);
        async_load16(WoT + (size_t)(n0 + arow) * DM + k0 + acol,     (char*)sBo + tid * 16);
        __syncthreads();

        bf16x8 af[4], bg[2], bo[2];
#pragma unroll
        for (int i = 0; i < 4; ++i)
            af[i] = *(const bf16x8*)&sA[(wm + i * 16 + rA) * 32 + kq];
#pragma unroll
        for (int j = 0; j < 2; ++j) {
            bg[j] = *(const bf16x8*)&sBg[(wn + j * 16 + rA) * 32 + kq];
            bo[j] = *(const bf16x8*)&sBo[(wn + j * 16 + rA) * 32 + kq];
        }
#pragma unroll
        for (int i = 0; i < 4; ++i)
#pragma unroll
            for (int j = 0; j < 2; ++j) {
                accG[i][j] = __builtin_amdgcn_mfma_f32_16x16x32_bf16(af[i], bg[j], accG[i][j], 0, 0, 0);
                accO[i][j] = __builtin_amdgcn_mfma_f32_16x16x32_bf16(af[i], bo[j], accO[i][j], 0, 0, 0);
            }
        __syncthreads();
    }

    const int colL = lane & 15;
    const int rowQ = (lane >> 4) * 4;
#pragma unroll
    for (int j = 0; j < 2; ++j) {
        const int n = n0 + wn + j * 16 + colL;
        const float bgv = bproj[n];
        const float bov = bproj[2048 + n];
#pragma unroll
        for (int i = 0; i < 4; ++i) {
            const int mbase = m0 + wm + i * 16 + rowQ;
#pragma unroll
            for (int r = 0; r < 4; ++r) {
                const float g = accG[i][j][r] + bgv;
                const float o = accO[i][j][r] + bov;
                const float h = g * (1.0f / (1.0f + __expf(-o)));
                H[(size_t)(mbase + r) * DM + n] = f2bf(h);
            }
        }
    }
}

// -------- GEMM2: Out[row] = H[row][:] @ WoutT^T + b, H split across 2 bases --
__global__ __launch_bounds__(256, 2)
void gemm2(const unsigned short* __restrict__ Hlo,
           const unsigned short* __restrict__ Hhi,
           const unsigned short* __restrict__ Bt,
           const float* __restrict__ bout,
           float* __restrict__ Out,
           int row_base) {
    __shared__ __align__(16) unsigned short sA[128 * 32];
    __shared__ __align__(16) unsigned short sB[128 * 32];

    const int tid  = threadIdx.x;
    const int wave = tid >> 6;
    const int lane = tid & 63;
    const int m0 = row_base + blockIdx.y * 128;   // global output row base
    const int n0 = blockIdx.x * 128;
    const int wm = (wave & 1) * 64;
    const int wn = (wave >> 1) * 64;

    const unsigned short* __restrict__ A =
        (m0 < 8192) ? (Hlo + (size_t)m0 * DM) : (Hhi + (size_t)(m0 - 8192) * DM);

    f32x4 acc[4][4];
#pragma unroll
    for (int i = 0; i < 4; ++i)
#pragma unroll
        for (int j = 0; j < 4; ++j) acc[i][j] = (f32x4){0.f, 0.f, 0.f, 0.f};

    const int arow = tid >> 2;
    const int acol = (tid & 3) * 8;
    const int kq = (lane >> 4) * 8;
    const int rA = lane & 15;

    for (int k0 = 0; k0 < DM; k0 += 32) {
        async_load16(A + (size_t)arow * DM + k0 + acol,        (char*)sA + tid * 16);
        async_load16(A + (size_t)(64 + arow) * DM + k0 + acol, (char*)sA + 4096 + tid * 16);
        async_load16(Bt + (size_t)(n0 + arow) * DM + k0 + acol,      (char*)sB + tid * 16);
        async_load16(Bt + (size_t)(n0 + 64 + arow) * DM + k0 + acol, (char*)sB + 4096 + tid * 16);
        __syncthreads();

        bf16x8 af[4], bfr[4];
#pragma unroll
        for (int i = 0; i < 4; ++i)
            af[i] = *(const bf16x8*)&sA[(wm + i * 16 + rA) * 32 + kq];
#pragma unroll
        for (int j = 0; j < 4; ++j)
            bfr[j] = *(const bf16x8*)&sB[(wn + j * 16 + rA) * 32 + kq];
#pragma unroll
        for (int i = 0; i < 4; ++i)
#pragma unroll
            for (int j = 0; j < 4; ++j)
                acc[i][j] = __builtin_amdgcn_mfma_f32_16x16x32_bf16(af[i], bfr[j], acc[i][j], 0, 0, 0);
        __syncthreads();
    }

    const int colL = lane & 15;
    const int rowQ = (lane >> 4) * 4;
#pragma unroll
    for (int j = 0; j < 4; ++j) {
        const int n = n0 + wn + j * 16 + colL;
        const float bv = bout[n];
#pragma unroll
        for (int i = 0; i < 4; ++i) {
            const int mbase = m0 + wm + i * 16 + rowQ;
#pragma unroll
            for (int r = 0; r < 4; ++r)
                Out[(size_t)(mbase + r) * DM + n] = acc[i][j][r] + bv;
        }
    }
}

extern "C" void kernel_launch(void* const* d_in, const int* in_sizes, int n_in,
                              void* d_out, int out_size, void* d_ws, size_t ws_size,
                              hipStream_t stream) {
    const float* x     = (const float*)d_in[0];   // [4,4096,1024] fp32
    const float* Wproj = (const float*)d_in[1];   // [1024,3072]   fp32
    const float* bproj = (const float*)d_in[2];   // [3072]        fp32
    const float* Wout  = (const float*)d_in[3];   // [1024,1024]   fp32
    const float* bout  = (const float*)d_in[4];   // [1024]        fp32
    float* out = (float*)d_out;                   // [4,4096,1024] fp32 (64 MB)

    unsigned short* Xb  = (unsigned short*)d_out; // shorts [0,16M): Xbf16 (phases 1-3)
    unsigned short* WgT   = (unsigned short*)d_ws;
    unsigned short* WoT   = WgT + MEG;
    unsigned short* WoutT = WgT + 2 * MEG;
    unsigned short* Hws   = WgT + 3 * MEG;

    // ws big enough for full H (3M weight shorts + 16M H shorts = 38 MB)?
    const bool big_ws = ws_size >= (size_t)19 * MEG * 2;

    // H bases: Hlo = rows 0..8191, Hhi = rows 8192..16383 (base at its row 8192)
    unsigned short* Hlo = big_ws ? Hws : ((unsigned short*)d_out + 16 * MEG);
    unsigned short* Hhi = big_ws ? (Hws + (size_t)8192 * DM) : Hws;

    // 1) Xbf16 (d_out lo) <- fp32 x
    conv_x<<<(MTOT * DM) / (256 * 8), 256, 0, stream>>>(x, Xb);

    // 2) transposed bf16 weight panels -> ws
    transpose_w<<<dim3(32, 32, 3), dim3(32, 8, 1), 0, stream>>>(Wproj, Wout, WgT);

    // 3) H = (X@Wg + bg) * sigmoid(X@Wo + bo), stored split across Hlo/Hhi
    gemm1_fused<<<dim3(DM / 64, MTOT / 128), 256, 0, stream>>>(
        Xb, WgT, WoT, bproj, Hlo, Hhi);

    // 4) out = H @ Wout + b_out
    if (big_ws) {
        // H fully in ws: no aliasing with out -> single launch, 1024 blocks
        gemm2<<<dim3(DM / 128, MTOT / 128), 256, 0, stream>>>(
            Hlo, Hhi, WoutT, bout, out, 0);
    } else {
        // lo half first (reads d_out-hi, writes d_out-lo: disjoint),
        // then hi half (reads only ws, overwrites the now-dead H-lo region)
        gemm2<<<dim3(DM / 128, 64), 256, 0, stream>>>(Hlo, Hhi, WoutT, bout, out, 0);
        gemm2<<<dim3(DM / 128, 64), 256, 0, stream>>>(Hlo, Hhi, WoutT, bout, out, 8192);
    }
}